// Round 9
// baseline (401.105 us; speedup 1.0000x reference)
//
#include <hip/hip_runtime.h>

// LSTM_Actor v8b: v7 + x-GEMM decoupled one step (in-wave) + short h-chains.
// (v8 with the macro/braced-initializer compile error fixed: named ZERO4.)
// 256 blocks x 512 threads (8 waves), 8 rows/block, persistent over t.
// Per step: accX(t+1) = bias + x(t+1)@W_ih computed from A-frags read LAST
// step (register-ready at barrier exit -> fills the A2/A3 ds_read shadow);
// h-part: two parallel 2-chains (Bhh onto accX(t), Bhl onto zero), merged in
// the pair-sum. x staged in a 4-slot LDS ring (write t+3, frag-read t+2
// mid-body). One lgkm-only barrier per step. Projection round-robin (w==t&7).
// A (M=16) = interleaved hi/lo rows; x hi-only; h + W_hh hi/lo (recurrent).

#define TT 512
#define BB 2048
#define DD 64
#define HH 64
#define AA 16
#define ROWB 768   // LDS bytes per A-row: x 4 slots x 128B | h 2 par x 128B

typedef short bf16x8 __attribute__((ext_vector_type(8)));
typedef float f32x4 __attribute__((ext_vector_type(4)));

#define MFMA16(a, b, c) __builtin_amdgcn_mfma_f32_16x16x32_bf16((a), (b), (c), 0, 0, 0)

#if defined(__has_builtin)
#  if __has_builtin(__builtin_amdgcn_exp2f)
#    define EXP2F(x) __builtin_amdgcn_exp2f(x)
#  else
#    define EXP2F(x) exp2f(x)
#  endif
#  if __has_builtin(__builtin_amdgcn_rcpf)
#    define RCPF(x) __builtin_amdgcn_rcpf(x)
#  else
#    define RCPF(x) (1.0f/(x))
#  endif
#else
#  define EXP2F(x) exp2f(x)
#  define RCPF(x) (1.0f/(x))
#endif

__device__ __forceinline__ float sigmoid_f(float x) {
  return RCPF(1.0f + EXP2F(-1.4426950408889634f * x));
}
__device__ __forceinline__ float tanh_f(float x) {
  return 1.0f - 2.0f * RCPF(1.0f + EXP2F(2.8853900817779268f * x));
}
__device__ __forceinline__ short f2bf(float f) {  // RNE fp32->bf16
  union { float f; unsigned u; } v; v.f = f;
  unsigned r = v.u + 0x7FFFu + ((v.u >> 16) & 1u);
  return (short)(r >> 16);
}
__device__ __forceinline__ float bf2f(short s) {
  union { unsigned u; float f; } v; v.u = ((unsigned)(unsigned short)s) << 16;
  return v.f;
}
// 16B-slot swizzle within a 128B region; extra (row&8) term breaks the
// hrow/hrow+4 write collision (4-way -> 2-way; 2-way is free).
__device__ __forceinline__ int swz(int row, int inner) {
  return (inner ^ (row & 7) ^ ((row & 8) >> 1)) & 7;
}

// lgkm-only barrier: LDS writes visible; global loads stay in flight.
__device__ __forceinline__ void block_sync_lds() {
  __builtin_amdgcn_sched_barrier(0);
  asm volatile("s_waitcnt lgkmcnt(0)" ::: "memory");
  __builtin_amdgcn_s_barrier();
  __builtin_amdgcn_sched_barrier(0);
}

__global__ __launch_bounds__(512, 2)
void lstm_actor_v8(const float* __restrict__ x,
                   const float* __restrict__ W_ih,
                   const float* __restrict__ W_hh,
                   const float* __restrict__ b_ih,
                   const float* __restrict__ b_hh,
                   const float* __restrict__ W_out,
                   const float* __restrict__ b_out,
                   float* __restrict__ out) {
  __shared__ __align__(16) unsigned short act[16 * ROWB / 2];  // 12 KB
  char* actb = (char*)act;

  const int tid  = threadIdx.x;
  const int lane = tid & 63;
  const int w    = tid >> 6;       // wave 0..7: j-slice j0 = 8w; x-stage row w
  const int lr   = lane & 15;
  const int lg   = lane >> 4;
  const int qq   = lr >> 3;        // 0/1: quadrant within tile pair
  const int jj   = lr & 7;
  const int r0   = blockIdx.x * 8;
  const int j0   = w * 8;

  const f32x4 ZERO4 = {0.f, 0.f, 0.f, 0.f};

  // ---- weights: W_ih hi, W_hh hi+lo; 2 packed N-tiles x 2 k-frags ----
  bf16x8 Bih[2][2], Bhh[2][2], Bhl[2][2];
  float biash[2];                  // 0.5*(b_ih+b_hh)
#pragma unroll
  for (int nt = 0; nt < 2; ++nt) {
    const int g = (nt * 2 + qq) * 64 + j0 + jj;
    biash[nt] = 0.5f * (b_ih[g] + b_hh[g]);
#pragma unroll
    for (int kt = 0; kt < 2; ++kt) {
      const float* si = W_ih + g * 64 + kt * 32 + lg * 8;
      const float* sh = W_hh + g * 64 + kt * 32 + lg * 8;
      bf16x8 vi, vh, vl;
#pragma unroll
      for (int u = 0; u < 8; ++u) {
        vi[u] = f2bf(si[u]);
        const float f = sh[u];
        const short hi = f2bf(f);
        vh[u] = hi;
        vl[u] = f2bf(f - bf2f(hi));
      }
      Bih[nt][kt] = vi; Bhh[nt][kt] = vh; Bhl[nt][kt] = vl;
    }
  }

  // ---- projection weights (all waves; hi only) ----
  bf16x8 pb[2];
  const float boh = 0.5f * b_out[lr];
#pragma unroll
  for (int kt = 0; kt < 2; ++kt) {
    const float* src = W_out + lr * 64 + kt * 32 + lg * 8;
    bf16x8 vh;
#pragma unroll
    for (int u = 0; u < 8; ++u) vh[u] = f2bf(src[u]);
    pb[kt] = vh;
  }

  // ---- LDS geometry ----
  // x A-frag read offsets (add slot*128): row lr, k-frag kt
  int aoffX[2], aoffH[2];
#pragma unroll
  for (int kt = 0; kt < 2; ++kt) {
    aoffX[kt] = lr * ROWB + swz(lr, kt * 4 + lg) * 16;
    aoffH[kt] = lr * ROWB + 512 + swz(lr, kt * 4 + lg) * 16;
  }
  // x stage write base (wave w stages real row w -> A-row 2w, hi only)
  const int xwb = (2 * w) * ROWB + swz(2 * w, lane >> 3) * 16 + ((2 * lane) & 15);
  // h write bases: lane owns (hrow = 2lg+qq, hj = j0+jj); inner slot = w
  const int hrow = 2 * lg + qq;
  const int hW_hi = (2 * hrow) * ROWB + 512 + swz(2 * hrow, w) * 16 + 2 * jj;
  const int hW_lo = (2 * hrow + 1) * ROWB + 512 + swz(2 * hrow + 1, w) * 16 + 2 * jj;

  // ---- zero LDS (h(-1)=0; x odd rows stay 0 forever) ----
  for (int i = tid; i < 16 * ROWB / 4; i += 512) ((unsigned*)act)[i] = 0u;
  __syncthreads();

  // ---- stage x(0),x(1),x(2) into slots 0,1,2 ----
  const float* xg0 = x + (size_t)(r0 + w) * DD + lane;
#pragma unroll
  for (int s = 0; s < 3; ++s) {
    const float v = xg0[(size_t)s * BB * DD];
    *(unsigned short*)(actb + xwb + s * 128) = (unsigned short)f2bf(v);
  }
  __syncthreads();

  // ---- prologue: accX(0) from x(0); A0n/A1n = x(1) frags ----
  f32x4 cX0 = {biash[0], biash[0], biash[0], biash[0]};
  f32x4 cX1 = {biash[1], biash[1], biash[1], biash[1]};
  {
    const bf16x8 A0c = *(const bf16x8*)(actb + aoffX[0]);
    const bf16x8 A1c = *(const bf16x8*)(actb + aoffX[1]);
    cX0 = MFMA16(A0c, Bih[0][0], cX0); cX0 = MFMA16(A1c, Bih[0][1], cX0);
    cX1 = MFMA16(A0c, Bih[1][0], cX1); cX1 = MFMA16(A1c, Bih[1][1], cX1);
  }
  bf16x8 A0n = *(const bf16x8*)(actb + aoffX[0] + 128);
  bf16x8 A1n = *(const bf16x8*)(actb + aoffX[1] + 128);

  float xw_reg = xg0[(size_t)3 * BB * DD];
  float xf_reg = xg0[(size_t)4 * BB * DD];
  const float* xg = xg0 + (size_t)5 * BB * DD;

  float c_state = 0.0f;

  for (int t = 0; t < TT; ++t) {
    const int hp  = (t & 1) << 7;    // h read parity (h(t-1))
    const int hpw = 128 - hp;        // h write parity (h(t))

    // ---- h(t-1) frag reads (120-cyc shadow filled by x-MFMAs below) ----
    const bf16x8 A2 = *(const bf16x8*)(actb + aoffH[0] + hp);
    const bf16x8 A3 = *(const bf16x8*)(actb + aoffH[1] + hp);

    // ---- accX(t+1): operands register-ready at barrier exit ----
    f32x4 nX0 = {biash[0], biash[0], biash[0], biash[0]};
    f32x4 nX1 = {biash[1], biash[1], biash[1], biash[1]};
    nX0 = MFMA16(A0n, Bih[0][0], nX0); nX0 = MFMA16(A1n, Bih[0][1], nX0);
    nX1 = MFMA16(A0n, Bih[1][0], nX1); nX1 = MFMA16(A1n, Bih[1][1], nX1);

    // ---- x(t+2) frag reads (latency hides under h-MFMA + activations) ----
    const int sl2 = ((t + 2) & 3) << 7;
    A0n = *(const bf16x8*)(actb + aoffX[0] + sl2);
    A1n = *(const bf16x8*)(actb + aoffX[1] + sl2);

    // ---- h-part: two parallel 2-chains per tile ----
    f32x4 P0 = MFMA16(A2, Bhh[0][0], cX0); P0 = MFMA16(A3, Bhh[0][1], P0);
    f32x4 Q0 = MFMA16(A2, Bhl[0][0], ZERO4);
    Q0 = MFMA16(A3, Bhl[0][1], Q0);
    f32x4 P1 = MFMA16(A2, Bhh[1][0], cX1); P1 = MFMA16(A3, Bhh[1][1], P1);
    f32x4 Q1 = MFMA16(A2, Bhl[1][0], ZERO4);
    Q1 = MFMA16(A3, Bhl[1][1], Q1);

    // ---- projection for out[t-1] on wave (t&7): A2/A3 = hs[t-1] ----
    const bool do_proj = (w == (t & 7)) && (t > 0);
    f32x4 pacc = {boh, boh, boh, boh};
    if (do_proj) {
      pacc = MFMA16(A2, pb[0], pacc);
      pacc = MFMA16(A3, pb[1], pacc);
    }

    // ---- merge + pair-sum + shfl redistribution ----
    const f32x4 S0 = P0 + Q0;
    const f32x4 S1 = P1 + Q1;
    const float a0 = S0[0] + S0[1], b0 = S0[2] + S0[3];
    const float a1 = S1[0] + S1[1], b1 = S1[2] + S1[3];
    const float rcv0 = __shfl_xor(qq ? a0 : b0, 8, 64);
    const float rcv1 = __shfl_xor(qq ? a1 : b1, 8, 64);
    const float iv_ = qq ? rcv0 : a0;
    const float fv_ = qq ? b0 : rcv0;
    const float gv_ = qq ? rcv1 : a1;
    const float ov_ = qq ? b1 : rcv1;

    // ---- elementwise (lane owns (hrow, j0+jj)) ----
    {
      const float iv = sigmoid_f(iv_);
      const float fv = sigmoid_f(fv_);
      const float gv = tanh_f(gv_);
      const float ov = sigmoid_f(ov_);
      c_state = fmaf(fv, c_state, iv * gv);
      const float h = ov * tanh_f(c_state);
      const short hh = f2bf(h);
      *(unsigned short*)(actb + hW_hi + hpw) = (unsigned short)hh;
      *(unsigned short*)(actb + hW_lo + hpw) = (unsigned short)f2bf(h - bf2f(hh));
    }

    // ---- x ring: write x(t+3); rotate register prefetch (load x(t+5)) ----
    if (t + 3 < TT) {
      *(unsigned short*)(actb + xwb + (((t + 3) & 3) << 7)) =
          (unsigned short)f2bf(xw_reg);
    }
    xw_reg = xf_reg;
    if (t + 5 < TT) xf_reg = *xg;
    xg += (size_t)BB * DD;

    // ---- projection stores ----
    if (do_proj) {
      const float oA = pacc[0] + pacc[1];
      const float oB = pacc[2] + pacc[3];
      const size_t base = ((size_t)(t - 1) * BB + r0 + 2 * lg) * AA + lr;
      out[base]      = oA;
      out[base + AA] = oB;
    }

    block_sync_lds();
    cX0 = nX0; cX1 = nX1;
  }

  // ---- epilogue: out[TT-1] from h(TT-1) (parity (TT&1)=0) ----
  if (w == (TT & 7)) {
    const bf16x8 A2 = *(const bf16x8*)(actb + aoffH[0]);
    const bf16x8 A3 = *(const bf16x8*)(actb + aoffH[1]);
    f32x4 pacc = {boh, boh, boh, boh};
    pacc = MFMA16(A2, pb[0], pacc);
    pacc = MFMA16(A3, pb[1], pacc);
    const float oA = pacc[0] + pacc[1];
    const float oB = pacc[2] + pacc[3];
    const size_t base = ((size_t)(TT - 1) * BB + r0 + 2 * lg) * AA + lr;
    out[base]      = oA;
    out[base + AA] = oB;
  }
}

extern "C" void kernel_launch(void* const* d_in, const int* in_sizes, int n_in,
                              void* d_out, int out_size, void* d_ws, size_t ws_size,
                              hipStream_t stream) {
  const float* x     = (const float*)d_in[0];
  const float* W_ih  = (const float*)d_in[1];
  const float* W_hh  = (const float*)d_in[2];
  const float* b_ih  = (const float*)d_in[3];
  const float* b_hh  = (const float*)d_in[4];
  const float* W_out = (const float*)d_in[5];
  const float* b_out = (const float*)d_in[6];
  float* out = (float*)d_out;

  lstm_actor_v8<<<dim3(BB / 8), dim3(512), 0, stream>>>(
      x, W_ih, W_hh, b_ih, b_hh, W_out, b_out, out);
}

// Round 10
// 399.299 us; speedup vs baseline: 1.0045x; 1.0045x over previous
//
#include <hip/hip_runtime.h>
#include <hip/hip_bf16.h>

// LSTM_Actor v9: x path fully in registers (no x LDS), DPP exchange, h-only LDS.
// 256 blocks x 512 threads (8 waves), 8 rows/block, persistent over t.
// Wave w owns j-slice [8w,8w+8) for all 4 quadrants as 2 packed N-tiles
// (tile0 {i,f}, tile1 {g,o}). A (M=16) = interleaved hi/lo rows; x hi-only
// (odd A-rows zero); h + W_hh hi/lo (recurrent path, fp32-level accuracy).
// Per step/wave: 12 gate MFMA. x A-frags converted in registers from global
// float4 loads (2-step prefetch, rides across the lgkm-only barrier; L1-served
// after wave 0). h exchange via 4KB dbuf LDS. shfl_xor(8) done as DPP
// row_ror:8 (VALU) - no ds_swizzle. One lgkm-only barrier/step.
// LDS pipe/CU/step: ~16 b128 reads + 16 b16 writes (~290cy vs v7's ~600cy).

#define TT 512
#define BB 2048
#define DD 64
#define HH 64
#define AA 16

typedef short bf16x8 __attribute__((ext_vector_type(8)));
typedef float f32x4 __attribute__((ext_vector_type(4)));

#define MFMA16(a, b, c) __builtin_amdgcn_mfma_f32_16x16x32_bf16((a), (b), (c), 0, 0, 0)

#if defined(__has_builtin)
#  if __has_builtin(__builtin_amdgcn_exp2f)
#    define EXP2F(x) __builtin_amdgcn_exp2f(x)
#  else
#    define EXP2F(x) exp2f(x)
#  endif
#  if __has_builtin(__builtin_amdgcn_rcpf)
#    define RCPF(x) __builtin_amdgcn_rcpf(x)
#  else
#    define RCPF(x) (1.0f/(x))
#  endif
#else
#  define EXP2F(x) exp2f(x)
#  define RCPF(x) (1.0f/(x))
#endif

__device__ __forceinline__ float sigmoid_f(float x) {
  return RCPF(1.0f + EXP2F(-1.4426950408889634f * x));
}
__device__ __forceinline__ float tanh_f(float x) {
  return 1.0f - 2.0f * RCPF(1.0f + EXP2F(2.8853900817779268f * x));
}
__device__ __forceinline__ short f2bf(float f) {  // RNE fp32->bf16
  union { float f; unsigned u; } v; v.f = f;
  unsigned r = v.u + 0x7FFFu + ((v.u >> 16) & 1u);
  return (short)(r >> 16);
}
__device__ __forceinline__ float bf2f(short s) {
  union { unsigned u; float f; } v; v.u = ((unsigned)(unsigned short)s) << 16;
  return v.f;
}
__device__ __forceinline__ unsigned cvtpk2(float a, float b) {  // [b|a] bf16 RNE
  union { __hip_bfloat162 b2; unsigned u; } cv;
  cv.b2 = __float22bfloat162_rn(make_float2(a, b));
  return cv.u;
}
// xor-by-8 across lanes via DPP row_ror:8 (16-lane rows; ror 8 == xor 8).
__device__ __forceinline__ float dpp_xor8(float v) {
  int i = __builtin_bit_cast(int, v);
  int r = __builtin_amdgcn_update_dpp(i, i, 0x128, 0xF, 0xF, true);
  return __builtin_bit_cast(float, r);
}
// 16B-slot swizzle within a 128B region.
__device__ __forceinline__ int swz(int row, int inner) {
  return (inner ^ (row & 7) ^ ((row & 8) >> 1)) & 7;
}
// lgkm-only barrier: LDS writes visible; global loads stay in flight.
__device__ __forceinline__ void block_sync_lds() {
  __builtin_amdgcn_sched_barrier(0);
  asm volatile("s_waitcnt lgkmcnt(0)" ::: "memory");
  __builtin_amdgcn_s_barrier();
  __builtin_amdgcn_sched_barrier(0);
}

__global__ __launch_bounds__(512, 2)
void lstm_actor_v9(const float* __restrict__ x,
                   const float* __restrict__ W_ih,
                   const float* __restrict__ W_hh,
                   const float* __restrict__ b_ih,
                   const float* __restrict__ b_hh,
                   const float* __restrict__ W_out,
                   const float* __restrict__ b_out,
                   float* __restrict__ out) {
  // h-only LDS: 16 A-rows x (2 parities x 128B) = 4 KB.
  __shared__ __align__(16) unsigned short act[16 * 128];
  char* actb = (char*)act;

  const int tid  = threadIdx.x;
  const int lane = tid & 63;
  const int w    = tid >> 6;       // wave 0..7: j-slice j0 = 8w
  const int lr   = lane & 15;
  const int lg   = lane >> 4;
  const int qq   = lr >> 3;        // 0/1: quadrant within tile pair
  const int jj   = lr & 7;
  const int r0   = blockIdx.x * 8;
  const int j0   = w * 8;

  const f32x4 ZERO4 = {0.f, 0.f, 0.f, 0.f};

  // ---- weights: W_ih hi, W_hh hi+lo; 2 packed N-tiles x 2 k-frags ----
  bf16x8 Bih[2][2], Bhh[2][2], Bhl[2][2];
  float biash[2];                  // 0.5*(b_ih+b_hh) splat (hi+lo rows sum)
#pragma unroll
  for (int nt = 0; nt < 2; ++nt) {
    const int g = (nt * 2 + qq) * 64 + j0 + jj;
    biash[nt] = 0.5f * (b_ih[g] + b_hh[g]);
#pragma unroll
    for (int kt = 0; kt < 2; ++kt) {
      const float* si = W_ih + g * 64 + kt * 32 + lg * 8;
      const float* sh = W_hh + g * 64 + kt * 32 + lg * 8;
      bf16x8 vi, vh, vl;
#pragma unroll
      for (int u = 0; u < 8; ++u) {
        vi[u] = f2bf(si[u]);
        const float f = sh[u];
        const short hi = f2bf(f);
        vh[u] = hi;
        vl[u] = f2bf(f - bf2f(hi));
      }
      Bih[nt][kt] = vi; Bhh[nt][kt] = vh; Bhl[nt][kt] = vl;
    }
  }

  // ---- projection weights (all waves; hi only) ----
  bf16x8 pb[2];
  const float boh = 0.5f * b_out[lr];
#pragma unroll
  for (int kt = 0; kt < 2; ++kt) {
    const float* src = W_out + lr * 64 + kt * 32 + lg * 8;
    bf16x8 vh;
#pragma unroll
    for (int u = 0; u < 8; ++u) vh[u] = f2bf(src[u]);
    pb[kt] = vh;
  }

  // ---- h LDS geometry ----
  int aoffH[2];
#pragma unroll
  for (int kt = 0; kt < 2; ++kt)
    aoffH[kt] = lr * 256 + swz(lr, kt * 4 + lg) * 16;
  const int hrow  = 2 * lg + qq;            // real row this lane owns
  const int hj    = j0 + jj;
  const int ar0   = 2 * hrow, ar1 = 2 * hrow + 1;
  const int hW_hi = ar0 * 256 + swz(ar0, w) * 16 + 2 * jj;
  const int hW_lo = ar1 * 256 + swz(ar1, w) * 16 + 2 * jj;

  // ---- x register-path geometry: even A-rows only (lr even = real row lr/2) ----
  const bool xactive = ((lr & 1) == 0);
  const int  xr      = lr >> 1;
  const float* xbase = x + (size_t)(r0 + xr) * DD + lg * 8;
  const size_t XSTEP = (size_t)BB * DD;

  // raw float buffers (zero for inactive lanes -> frags convert to 0)
  float4 RA0, RA1, RA2, RA3, RB0, RB1, RB2, RB3, T0, T1, T2, T3;
  RA0 = RA1 = RA2 = RA3 = make_float4(0.f, 0.f, 0.f, 0.f);
  RB0 = RB1 = RB2 = RB3 = RA0;
  T0 = T1 = T2 = T3 = RA0;
  if (xactive) {
    T0  = *(const float4*)(xbase);            // x(0)
    T1  = *(const float4*)(xbase + 4);
    T2  = *(const float4*)(xbase + 32);
    T3  = *(const float4*)(xbase + 36);
    RA0 = *(const float4*)(xbase + XSTEP);    // x(1)
    RA1 = *(const float4*)(xbase + XSTEP + 4);
    RA2 = *(const float4*)(xbase + XSTEP + 32);
    RA3 = *(const float4*)(xbase + XSTEP + 36);
    RB0 = *(const float4*)(xbase + 2 * XSTEP);// x(2)
    RB1 = *(const float4*)(xbase + 2 * XSTEP + 4);
    RB2 = *(const float4*)(xbase + 2 * XSTEP + 32);
    RB3 = *(const float4*)(xbase + 2 * XSTEP + 36);
  }
  bf16x8 XA0, XA1, XB0, XB1;
  {
    unsigned* u0 = (unsigned*)&XA0; unsigned* u1 = (unsigned*)&XA1;
    u0[0] = cvtpk2(T0.x, T0.y); u0[1] = cvtpk2(T0.z, T0.w);
    u0[2] = cvtpk2(T1.x, T1.y); u0[3] = cvtpk2(T1.z, T1.w);
    u1[0] = cvtpk2(T2.x, T2.y); u1[1] = cvtpk2(T2.z, T2.w);
    u1[2] = cvtpk2(T3.x, T3.y); u1[3] = cvtpk2(T3.z, T3.w);
  }

  // ---- zero h LDS (h(-1)=0, both parities) ----
  for (int i = tid; i < 16 * 128 / 2; i += 512) ((unsigned*)act)[i] = 0u;

  float c_state = 0.0f;
  __syncthreads();

  // step body: uses XU frags (x(t)); converts RC (x(t+1)) -> XP; issues loads
  // x(t+3) -> RC (freed). One lgkm-only barrier at the end.
  auto step = [&](int t, const bf16x8& XU0, const bf16x8& XU1,
                  bf16x8& XP0, bf16x8& XP1,
                  float4& R0, float4& R1, float4& R2, float4& R3) {
    const int hp  = (t & 1) << 7;    // h read parity (h(t-1))
    const int hpw = 128 - hp;        // h write parity (h(t))

    // h(t-1) frag reads; x-MFMAs below issue in their latency shadow
    const bf16x8 A2 = *(const bf16x8*)(actb + aoffH[0] + hp);
    const bf16x8 A3 = *(const bf16x8*)(actb + aoffH[1] + hp);

    // gate GEMM: x-part first (regs ready), then h hi chain; lo parallel
    f32x4 P0 = {biash[0], biash[0], biash[0], biash[0]};
    f32x4 P1 = {biash[1], biash[1], biash[1], biash[1]};
    P0 = MFMA16(XU0, Bih[0][0], P0);  P1 = MFMA16(XU0, Bih[1][0], P1);
    P0 = MFMA16(XU1, Bih[0][1], P0);  P1 = MFMA16(XU1, Bih[1][1], P1);
    P0 = MFMA16(A2, Bhh[0][0], P0);   P1 = MFMA16(A2, Bhh[1][0], P1);
    P0 = MFMA16(A3, Bhh[0][1], P0);   P1 = MFMA16(A3, Bhh[1][1], P1);
    f32x4 Q0 = MFMA16(A2, Bhl[0][0], ZERO4);
    f32x4 Q1 = MFMA16(A2, Bhl[1][0], ZERO4);
    Q0 = MFMA16(A3, Bhl[0][1], Q0);
    Q1 = MFMA16(A3, Bhl[1][1], Q1);

    // projection for out[t-1] on wave (t&7): A2/A3 = hs[t-1]
    const bool do_proj = (w == (t & 7)) && (t > 0);
    f32x4 pacc = {boh, boh, boh, boh};
    if (do_proj) {
      pacc = MFMA16(A2, pb[0], pacc);
      pacc = MFMA16(A3, pb[1], pacc);
    }

    // convert x(t+1) raw -> XP (overlaps MFMA); then reuse RC for x(t+3) loads
    {
      unsigned* u0 = (unsigned*)&XP0; unsigned* u1 = (unsigned*)&XP1;
      u0[0] = cvtpk2(R0.x, R0.y); u0[1] = cvtpk2(R0.z, R0.w);
      u0[2] = cvtpk2(R1.x, R1.y); u0[3] = cvtpk2(R1.z, R1.w);
      u1[0] = cvtpk2(R2.x, R2.y); u1[1] = cvtpk2(R2.z, R2.w);
      u1[2] = cvtpk2(R3.x, R3.y); u1[3] = cvtpk2(R3.z, R3.w);
    }
    if (xactive && (t + 3 < TT)) {
      const float* p = xbase + (size_t)(t + 3) * XSTEP;
      R0 = *(const float4*)(p);
      R1 = *(const float4*)(p + 4);
      R2 = *(const float4*)(p + 32);
      R3 = *(const float4*)(p + 36);
    }

    // merge + pair-sum + DPP xor8 redistribution
    const f32x4 S0 = P0 + Q0;
    const f32x4 S1 = P1 + Q1;
    const float a0 = S0[0] + S0[1], b0 = S0[2] + S0[3];
    const float a1 = S1[0] + S1[1], b1 = S1[2] + S1[3];
    const float rcv0 = dpp_xor8(qq ? a0 : b0);
    const float rcv1 = dpp_xor8(qq ? a1 : b1);
    const float iv_ = qq ? rcv0 : a0;
    const float fv_ = qq ? b0 : rcv0;
    const float gv_ = qq ? rcv1 : a1;
    const float ov_ = qq ? b1 : rcv1;

    // elementwise (lane owns (hrow, hj)); h hi/lo -> LDS write parity
    {
      const float iv = sigmoid_f(iv_);
      const float fv = sigmoid_f(fv_);
      const float gv = tanh_f(gv_);
      const float ov = sigmoid_f(ov_);
      c_state = fmaf(fv, c_state, iv * gv);
      const float h = ov * tanh_f(c_state);
      const short hh = f2bf(h);
      *(unsigned short*)(actb + hW_hi + hpw) = (unsigned short)hh;
      *(unsigned short*)(actb + hW_lo + hpw) = (unsigned short)f2bf(h - bf2f(hh));
    }

    if (do_proj) {
      const float oA = pacc[0] + pacc[1];
      const float oB = pacc[2] + pacc[3];
      const size_t base = ((size_t)(t - 1) * BB + r0 + 2 * lg) * AA + lr;
      out[base]      = oA;
      out[base + AA] = oB;
    }

    block_sync_lds();
  };

  for (int t = 0; t < TT; t += 2) {
    step(t,     XA0, XA1, XB0, XB1, RA0, RA1, RA2, RA3);
    step(t + 1, XB0, XB1, XA0, XA1, RB0, RB1, RB2, RB3);
  }

  // ---- epilogue: out[TT-1] from h(TT-1) (parity (TT&1)=0) ----
  if (w == (TT & 7)) {
    const bf16x8 A2 = *(const bf16x8*)(actb + aoffH[0]);
    const bf16x8 A3 = *(const bf16x8*)(actb + aoffH[1]);
    f32x4 pacc = {boh, boh, boh, boh};
    pacc = MFMA16(A2, pb[0], pacc);
    pacc = MFMA16(A3, pb[1], pacc);
    const float oA = pacc[0] + pacc[1];
    const float oB = pacc[2] + pacc[3];
    const size_t base = ((size_t)(TT - 1) * BB + r0 + 2 * lg) * AA + lr;
    out[base]      = oA;
    out[base + AA] = oB;
  }
}

extern "C" void kernel_launch(void* const* d_in, const int* in_sizes, int n_in,
                              void* d_out, int out_size, void* d_ws, size_t ws_size,
                              hipStream_t stream) {
  const float* x     = (const float*)d_in[0];
  const float* W_ih  = (const float*)d_in[1];
  const float* W_hh  = (const float*)d_in[2];
  const float* b_ih  = (const float*)d_in[3];
  const float* b_hh  = (const float*)d_in[4];
  const float* W_out = (const float*)d_in[5];
  const float* b_out = (const float*)d_in[6];
  float* out = (float*)d_out;

  lstm_actor_v9<<<dim3(BB / 8), dim3(512), 0, stream>>>(
      x, W_ih, W_hh, b_ih, b_hh, W_out, b_out, out);
}

// Round 11
// 213.057 us; speedup vs baseline: 1.8826x; 1.8741x over previous
//
#include <hip/hip_runtime.h>
#include <hip/hip_bf16.h>

// LSTM_Actor v10: v7 skeleton, pure-bf16 recurrent + x-pair M-packing.
// 256 blocks x 512 threads (8 waves), 8 rows/block, persistent over t.
// A (M=16) rows: even row 2q = real row q, odd row 2q+1 = x(t+1) row q (x
// region) / zero (h region). One x-pass per 2 steps computes xpart(t) AND
// xpart(t+1) (held in C regs across the barrier). Per step/wave: 4 h-MFMA
// (+2 x-MFMA amortized + 2 proj round-robin). All weights/acts bf16 hi-only
// (fallback if absmax>1.1e-2: re-add hi/lo). One lgkm-only barrier per step.
// DPP row_ror:8 for the gate exchange (VALU, no LDS). x staged float2/lane,
// cvt_pk, one b32 LDS write per 2 steps.

#define TT 512
#define BB 2048
#define DD 64
#define AA 16
#define ROWB 512   // bytes per A-row: x[par0|par1] 256B | h[par0|par1] 256B

typedef short bf16x8 __attribute__((ext_vector_type(8)));
typedef float f32x4 __attribute__((ext_vector_type(4)));

#define MFMA16(a, b, c) __builtin_amdgcn_mfma_f32_16x16x32_bf16((a), (b), (c), 0, 0, 0)

#if defined(__has_builtin)
#  if __has_builtin(__builtin_amdgcn_exp2f)
#    define EXP2F(x) __builtin_amdgcn_exp2f(x)
#  else
#    define EXP2F(x) exp2f(x)
#  endif
#  if __has_builtin(__builtin_amdgcn_rcpf)
#    define RCPF(x) __builtin_amdgcn_rcpf(x)
#  else
#    define RCPF(x) (1.0f/(x))
#  endif
#else
#  define EXP2F(x) exp2f(x)
#  define RCPF(x) (1.0f/(x))
#endif

__device__ __forceinline__ float sigmoid_f(float x) {
  return RCPF(1.0f + EXP2F(-1.4426950408889634f * x));
}
__device__ __forceinline__ float tanh_f(float x) {
  return 1.0f - 2.0f * RCPF(1.0f + EXP2F(2.8853900817779268f * x));
}
__device__ __forceinline__ unsigned short bfu(float f) {  // RNE fp32->bf16 bits
  union { __hip_bfloat16 b; unsigned short u; } cv;
  cv.b = __float2bfloat16(f);
  return cv.u;
}
__device__ __forceinline__ unsigned cvtpk2(float a, float b) {  // [b|a] bf16 RNE
  union { __hip_bfloat162 b2; unsigned u; } cv;
  cv.b2 = __float22bfloat162_rn(make_float2(a, b));
  return cv.u;
}
// xor-by-8 across lanes via DPP row_ror:8 (validated in v9).
__device__ __forceinline__ float dpp_xor8(float v) {
  int i = __builtin_bit_cast(int, v);
  int r = __builtin_amdgcn_update_dpp(i, i, 0x128, 0xF, 0xF, true);
  return __builtin_bit_cast(float, r);
}
// 16B-slot swizzle within a 128B region (8 slots); (row&8) term breaks the
// row/row+8 collision.
__device__ __forceinline__ int swz(int row, int slot) {
  return (slot ^ (row & 7) ^ ((row & 8) >> 1)) & 7;
}
// lgkm-only barrier: LDS writes visible; global loads stay in flight.
__device__ __forceinline__ void block_sync_lds() {
  __builtin_amdgcn_sched_barrier(0);
  asm volatile("s_waitcnt lgkmcnt(0)" ::: "memory");
  __builtin_amdgcn_s_barrier();
  __builtin_amdgcn_sched_barrier(0);
}

__global__ __launch_bounds__(512, 2)
void lstm_actor_v10(const float* __restrict__ x,
                    const float* __restrict__ W_ih,
                    const float* __restrict__ W_hh,
                    const float* __restrict__ b_ih,
                    const float* __restrict__ b_hh,
                    const float* __restrict__ W_out,
                    const float* __restrict__ b_out,
                    float* __restrict__ out) {
  __shared__ __align__(16) unsigned short act[16 * ROWB / 2];  // 8 KB
  char* actb = (char*)act;

  const int tid  = threadIdx.x;
  const int lane = tid & 63;
  const int w    = tid >> 6;       // wave 0..7: j-slice j0 = 8w
  const int lr   = lane & 15;
  const int lg   = lane >> 4;
  const int qq   = lr >> 3;        // 0/1: quadrant within tile pair
  const int jj   = lr & 7;
  const int r0   = blockIdx.x * 8;
  const int j0   = w * 8;

  const f32x4 Z = {0.f, 0.f, 0.f, 0.f};

  // ---- weights (all hi-only bf16): 2 packed N-tiles x 2 k-frags each ----
  bf16x8 Bih[2][2], Bhh[2][2];
  float biasv[2];                  // FULL bias (each gate row counted once)
#pragma unroll
  for (int nt = 0; nt < 2; ++nt) {
    const int g = (nt * 2 + qq) * 64 + j0 + jj;
    biasv[nt] = b_ih[g] + b_hh[g];
#pragma unroll
    for (int kt = 0; kt < 2; ++kt) {
      const float* si = W_ih + g * 64 + kt * 32 + lg * 8;
      const float* sh = W_hh + g * 64 + kt * 32 + lg * 8;
      bf16x8 vi, vh;
#pragma unroll
      for (int u = 0; u < 8; ++u) {
        vi[u] = (short)bfu(si[u]);
        vh[u] = (short)bfu(sh[u]);
      }
      Bih[nt][kt] = vi; Bhh[nt][kt] = vh;
    }
  }

  // ---- projection weights (all waves; hi only) ----
  bf16x8 pb[2];
  const float bo = b_out[lr];
#pragma unroll
  for (int kt = 0; kt < 2; ++kt) {
    const float* src = W_out + lr * 64 + kt * 32 + lg * 8;
    bf16x8 vh;
#pragma unroll
    for (int u = 0; u < 8; ++u) vh[u] = (short)bfu(src[u]);
    pb[kt] = vh;
  }

  // ---- LDS geometry ----
  int aoffX[2], aoffH[2];          // A-frag reads: row lr, k-frag kt
#pragma unroll
  for (int kt = 0; kt < 2; ++kt) {
    aoffX[kt] = lr * ROWB +       swz(lr, kt * 4 + lg) * 16;
    aoffH[kt] = lr * ROWB + 256 + swz(lr, kt * 4 + lg) * 16;
  }
  // h write: lane owns (hrow = 2lg+qq, hj = j0+jj) -> A-row 2*hrow (even)
  const int hrow = 2 * lg + qq;
  const int hj   = j0 + jj;
  const int hWb  = (2 * hrow) * ROWB + 256 + swz(2 * hrow, hj >> 3) * 16 + ((hj * 2) & 15);
  // x write: lane covers (xrow = 2w + lane/32, xj = 2*(lane&31)), b32 packed
  const int xrow = 2 * w + (lane >> 5);
  const int xj   = 2 * (lane & 31);
  const int xWb  = xrow * ROWB + swz(xrow, xj >> 3) * 16 + ((2 * xj) & 15);

  // ---- zero LDS (odd-row h region stays zero forever; h(-1)=0) ----
  for (int i = tid; i < 16 * ROWB / 4; i += 512) ((unsigned*)act)[i] = 0u;
  __syncthreads();

  // ---- x staging pointers: lane's float2 for time 2it+2+(lane>>5) ----
  const float* xgl = x + (size_t)(r0 + w) * DD + xj + (size_t)(lane >> 5) * BB * DD;
  // prologue: stage x(0),x(1) into par0
  {
    const float2 v = *(const float2*)xgl;
    *(unsigned*)(actb + xWb) = cvtpk2(v.x, v.y);
  }
  float2 xw = *(const float2*)(xgl + (size_t)2 * BB * DD);  // x(2)/x(3)
  float2 xf = *(const float2*)(xgl + (size_t)4 * BB * DD);  // x(4)/x(5)
  xgl += (size_t)6 * BB * DD;

  float c_state = 0.0f;
  __syncthreads();

  f32x4 xCa, xCb;   // xpart accs: m0/m2 = step A rows, m1/m3 = step B rows

  for (int it = 0; it < TT / 2; ++it) {
    const int xpR = (it & 1) << 7;
    const int xpW = 128 - xpR;

    // ================= step A: t = 2it (h read par0, write par1) =========
    {
      const int t = 2 * it;
      const bf16x8 A2 = *(const bf16x8*)(actb + aoffH[0]);        // h par0
      const bf16x8 A3 = *(const bf16x8*)(actb + aoffH[1]);
      const bf16x8 X0 = *(const bf16x8*)(actb + aoffX[0] + xpR);  // x pair
      const bf16x8 X1 = *(const bf16x8*)(actb + aoffX[1] + xpR);

      // x-pass: xpart(t) in m0/m2, xpart(t+1) in m1/m3; bias folded in
      xCa = (f32x4){biasv[0], biasv[0], biasv[0], biasv[0]};
      xCb = (f32x4){biasv[1], biasv[1], biasv[1], biasv[1]};
      xCa = MFMA16(X0, Bih[0][0], xCa); xCa = MFMA16(X1, Bih[0][1], xCa);
      xCb = MFMA16(X0, Bih[1][0], xCb); xCb = MFMA16(X1, Bih[1][1], xCb);

      // h-pass (odd A-rows are zero -> m1/m3 garbage unused)
      f32x4 H0 = MFMA16(A2, Bhh[0][0], Z); H0 = MFMA16(A3, Bhh[0][1], H0);
      f32x4 H1 = MFMA16(A2, Bhh[1][0], Z); H1 = MFMA16(A3, Bhh[1][1], H1);

      // projection out[t-1] on wave (t&7)
      const bool do_proj = (w == (t & 7)) && (t > 0);
      f32x4 pacc = Z;
      if (do_proj) {
        pacc = MFMA16(A2, pb[0], Z);
        pacc = MFMA16(A3, pb[1], pacc);
      }

      // gates(t): rows 2lg (a), 2lg+1 (b)
      const float a0 = H0[0] + xCa[0], b0 = H0[2] + xCa[2];
      const float a1 = H1[0] + xCb[0], b1 = H1[2] + xCb[2];
      const float rcv0 = dpp_xor8(qq ? a0 : b0);
      const float rcv1 = dpp_xor8(qq ? a1 : b1);
      const float iv_ = qq ? rcv0 : a0;
      const float fv_ = qq ? b0 : rcv0;
      const float gv_ = qq ? rcv1 : a1;
      const float ov_ = qq ? b1 : rcv1;

      const float iv = sigmoid_f(iv_);
      const float fv = sigmoid_f(fv_);
      const float gv = tanh_f(gv_);
      const float ov = sigmoid_f(ov_);
      c_state = fmaf(fv, c_state, iv * gv);
      const float h = ov * tanh_f(c_state);
      *(unsigned short*)(actb + hWb + 128) = bfu(h);   // h(t) -> par1

      // x stage: write x(t+2)/x(t+3) pair; rotate; issue loads x(t+6)/(t+7)
      *(unsigned*)(actb + xWb + xpW) = cvtpk2(xw.x, xw.y);
      xw = xf;
      if (it < TT / 2 - 3) xf = *(const float2*)xgl;
      xgl += (size_t)2 * BB * DD;

      if (do_proj) {
        const size_t base = ((size_t)(t - 1) * BB + r0 + 2 * lg) * AA + lr;
        out[base]      = pacc[0] + bo;
        out[base + AA] = pacc[2] + bo;
      }
      block_sync_lds();
    }

    // ================= step B: t = 2it+1 (h read par1, write par0) =======
    {
      const int t = 2 * it + 1;
      const bf16x8 A2 = *(const bf16x8*)(actb + aoffH[0] + 128);  // h par1
      const bf16x8 A3 = *(const bf16x8*)(actb + aoffH[1] + 128);

      f32x4 H0 = MFMA16(A2, Bhh[0][0], Z); H0 = MFMA16(A3, Bhh[0][1], H0);
      f32x4 H1 = MFMA16(A2, Bhh[1][0], Z); H1 = MFMA16(A3, Bhh[1][1], H1);

      const bool do_proj = (w == (t & 7));
      f32x4 pacc = Z;
      if (do_proj) {
        pacc = MFMA16(A2, pb[0], Z);
        pacc = MFMA16(A3, pb[1], pacc);
      }

      // gates(t+... ): x from carried regs m1/m3
      const float a0 = H0[0] + xCa[1], b0 = H0[2] + xCa[3];
      const float a1 = H1[0] + xCb[1], b1 = H1[2] + xCb[3];
      const float rcv0 = dpp_xor8(qq ? a0 : b0);
      const float rcv1 = dpp_xor8(qq ? a1 : b1);
      const float iv_ = qq ? rcv0 : a0;
      const float fv_ = qq ? b0 : rcv0;
      const float gv_ = qq ? rcv1 : a1;
      const float ov_ = qq ? b1 : rcv1;

      const float iv = sigmoid_f(iv_);
      const float fv = sigmoid_f(fv_);
      const float gv = tanh_f(gv_);
      const float ov = sigmoid_f(ov_);
      c_state = fmaf(fv, c_state, iv * gv);
      const float h = ov * tanh_f(c_state);
      *(unsigned short*)(actb + hWb) = bfu(h);         // h(t) -> par0

      if (do_proj) {
        const size_t base = ((size_t)(t - 1) * BB + r0 + 2 * lg) * AA + lr;
        out[base]      = pacc[0] + bo;
        out[base + AA] = pacc[2] + bo;
      }
      block_sync_lds();
    }
  }

  // ---- epilogue: out[TT-1] from h(TT-1) (written to par0) ----
  if (w == (TT & 7)) {
    const bf16x8 A2 = *(const bf16x8*)(actb + aoffH[0]);
    const bf16x8 A3 = *(const bf16x8*)(actb + aoffH[1]);
    f32x4 pacc = MFMA16(A2, pb[0], Z);
    pacc = MFMA16(A3, pb[1], pacc);
    const size_t base = ((size_t)(TT - 1) * BB + r0 + 2 * lg) * AA + lr;
    out[base]      = pacc[0] + bo;
    out[base + AA] = pacc[2] + bo;
  }
}

extern "C" void kernel_launch(void* const* d_in, const int* in_sizes, int n_in,
                              void* d_out, int out_size, void* d_ws, size_t ws_size,
                              hipStream_t stream) {
  const float* x     = (const float*)d_in[0];
  const float* W_ih  = (const float*)d_in[1];
  const float* W_hh  = (const float*)d_in[2];
  const float* b_ih  = (const float*)d_in[3];
  const float* b_hh  = (const float*)d_in[4];
  const float* W_out = (const float*)d_in[5];
  const float* b_out = (const float*)d_in[6];
  float* out = (float*)d_out;

  lstm_actor_v10<<<dim3(BB / 8), dim3(512), 0, stream>>>(
      x, W_ih, W_hh, b_ih, b_hh, W_out, b_out, out);
}